// Round 7
// baseline (349.228 us; speedup 1.0000x reference)
//
#include <hip/hip_runtime.h>
#include <hip/hip_bf16.h>

// ---------------------------------------------------------------------------
// DGL GAT (2-layer, heads=4, out=32) + WeightedSumAndMax readout.
// Round 23: (a) MFMA C-stores: per-wave LDS transpose staging (XOR-swizzled,
//           no barriers) -> full-row dwordx4 stores; kills the 2B-scatter
//           write amplification seen in WRITE_SIZE (86.6 vs 58 MB payload).
//           (b) dependency-true fusion: WT-pack + deg/ticket zero -> prep0
//           (replaces memset); hist fuses with mfma_dual (independent);
//           scatter is its own dispatch again (clean counters).
//           agg kernels frozen at r22. 8 dispatches.
// ---------------------------------------------------------------------------

#define HEADS 4
#define OUTF 32
#define HF 128            // HEADS*OUTF
#define IN_FEATS 74
#define PRED_DIM 128
#define NEG_SLOPE 0.2f
#define NEG_INF_ENC 0x007fffffu   // enc_f(-inf)
#define LOG2E 1.4426950408889634f
#define KP1 48            // kpairs for K=74 (padded to 96)
#define KP2 64            // kpairs for K=128

typedef __hip_bfloat16 bf16;
typedef __hip_bfloat162 bf16x2;
typedef __attribute__((ext_vector_type(8))) short bf16x8v;  // 8 bf16, 4 VGPRs
typedef __attribute__((ext_vector_type(4))) float f32x4v;   // MFMA C/D
typedef __attribute__((ext_vector_type(2))) float f32x2v;   // packed fp32

__device__ __forceinline__ unsigned enc_f(float f) {
  unsigned u = __float_as_uint(f);
  return (u & 0x80000000u) ? ~u : (u | 0x80000000u);
}
__device__ __forceinline__ float dec_f(unsigned k) {
  return (k & 0x80000000u) ? __uint_as_float(k & 0x7fffffffu)
                           : __uint_as_float(~k);
}
__device__ __forceinline__ unsigned pack_bf16(float a, float b) {
  bf16x2 h = __float22bfloat162_rn(make_float2(a, b));
  return *(unsigned*)&h;
}
__device__ __forceinline__ float2 unpack_bf16(unsigned u) {
  bf16x2 h = *(bf16x2*)&u;
  return __bfloat1622float2(h);
}
__device__ __forceinline__ float lrelu(float v) {
  return fmaxf(v, NEG_SLOPE * v);
}

// ===== prep0: zero deg+ticket, pack WT1/2/3 (replaces hipMemsetAsync) =====
__global__ __launch_bounds__(256) void prep0(
    const float* __restrict__ W1, const float* __restrict__ W2,
    const float* __restrict__ W3, unsigned* __restrict__ WT1,
    unsigned* __restrict__ WT2, unsigned* __restrict__ WT3,
    int* __restrict__ deg, int N) {
  int t = blockIdx.x * 256 + threadIdx.x;
  if (t <= N) deg[t] = 0;                    // deg[N] is the scan ticket
  if (t < 128 * KP1) {
    int c = t / KP1, kp = t % KP1;
    int k = kp * 2;
    float a1 = (k < IN_FEATS) ? W1[k * HF + c] : 0.f;
    float b1 = (k + 1 < IN_FEATS) ? W1[(k + 1) * HF + c] : 0.f;
    float a2 = (k < IN_FEATS) ? W2[k * HF + c] : 0.f;
    float b2 = (k + 1 < IN_FEATS) ? W2[(k + 1) * HF + c] : 0.f;
    WT1[t] = pack_bf16(a1, b1);
    WT2[t] = pack_bf16(a2, b2);
  } else if (t - 128 * KP1 < 128 * KP2) {
    int u = t - 128 * KP1;
    int c = u / KP2, kp = u % KP2;
    int k = kp * 2;
    WT3[u] = pack_bf16(W3[k * HF + c], W3[(k + 1) * HF + c]);
  }
}

// ===== scan1 + scan2 fused via last-block ticket; also writes row_ptr[N] ===
// row_ptr[0..N-1] hold per-2048-chunk partial scans; consumers add
// bpre[idx>>11]. row_ptr[N] = E - bpre[N>>11] so the fold is uniform.
__global__ __launch_bounds__(256) void scan12_kernel(
    const int* __restrict__ deg, int* __restrict__ row_ptr,
    int* __restrict__ bsum, int* __restrict__ bpre,
    int* __restrict__ ticket, int N, int E) {
  const int base = blockIdx.x * 2048;
  const int tbase = base + threadIdx.x * 8;
  int vals[8];
  int tsum = 0;
#pragma unroll
  for (int i = 0; i < 8; ++i) {
    int idx = tbase + i;
    vals[i] = (idx < N) ? deg[idx] : 0;
    tsum += vals[i];
  }
  const int lane = threadIdx.x & 63, wv = threadIdx.x >> 6;
  int incl = tsum;
#pragma unroll
  for (int off = 1; off < 64; off <<= 1) {
    int nv = __shfl_up(incl, off);
    if (lane >= off) incl += nv;
  }
  __shared__ int wsum[4];
  __shared__ int isLast;
  if (lane == 63) wsum[wv] = incl;
  __syncthreads();
  int woff = 0;
  for (int w = 0; w < wv; ++w) woff += wsum[w];
  int run = woff + incl - tsum;
#pragma unroll
  for (int i = 0; i < 8; ++i) {
    int idx = tbase + i;
    if (idx < N) row_ptr[idx] = run;
    run += vals[i];
  }
  if (threadIdx.x == 255) {
    bsum[blockIdx.x] = woff + incl;
    __threadfence();                       // publish bsum before ticket
    int t = atomicAdd(ticket, 1);
    isLast = (t == (int)gridDim.x - 1);
  }
  __syncthreads();
  if (isLast) {
    if (threadIdx.x < 64) {
      __threadfence();                     // acquire all bsum stores
      const int NB = gridDim.x;
      int running = 0;
      for (int c = 0; c < NB; c += 64) {
        int v = (c + lane < NB) ? bsum[c + lane] : 0;
        int incl2 = v;
#pragma unroll
        for (int off = 1; off < 64; off <<= 1) {
          int nv = __shfl_up(incl2, off);
          if (lane >= off) incl2 += nv;
        }
        if (c + lane < NB) bpre[c + lane] = running + incl2 - v;
        running += __shfl(incl2, 63);
      }
    }
    __syncthreads();                       // drain bpre stores (same CU)
    if (threadIdx.x == 0) row_ptr[N] = E - bpre[N >> 11];
  }
}

// ============== scatter (own dispatch again; folds bpre) ===================
__global__ __launch_bounds__(256) void scatter_kernel(
    const int* __restrict__ src, const int* __restrict__ dst,
    const int* __restrict__ row_ptr, const int* __restrict__ bpre,
    const int* __restrict__ rank, int* __restrict__ ssorted, int E) {
  int e = blockIdx.x * 256 + threadIdx.x;
  if (e >= E) return;
  if (e < 16) ssorted[E + e] = 0;
  int d = dst[e];
  ssorted[row_ptr[d] + bpre[d >> 11] + rank[e]] = src[e];
}

// ===================== MFMA node GEMM building blocks ======================
// Fragment mapping (16x16x32 bf16): lane (cc,q) of wave w:
//   A: row n0 + w*16 + cc, kpairs q*4 .. q*4+3
//   B: row t*16 + cc of WT (pre-packed (c,kp)), same kpair window
//   C/D: col t*16 + cc, rows n0 + w*16 + q*4 + r

template <int K>
__device__ __forceinline__ bf16x8v load_a_f32(const float* __restrict__ X,
                                              int row, int N, int ks, int q) {
  unsigned v[4] = {0u, 0u, 0u, 0u};
  if (row < N) {
    const float* base = X + (size_t)row * K;
    int k = ks * 32 + q * 8;
#pragma unroll
    for (int j = 0; j < 4; ++j) {
      int kk = k + j * 2;
      if (kk + 1 < K) {
        float2 f = *(const float2*)&base[kk];
        v[j] = pack_bf16(f.x, f.y);
      } else if (kk < K) {
        v[j] = pack_bf16(base[kk], 0.f);
      }
    }
  }
  union { unsigned u[4]; bf16x8v v8; } r;
  r.u[0] = v[0]; r.u[1] = v[1]; r.u[2] = v[2]; r.u[3] = v[3];
  return r.v8;
}

__device__ __forceinline__ void scores_epilogue(
    const f32x4v* acc, const float* __restrict__ attn_l,
    const float* __restrict__ attn_r, float* __restrict__ el,
    float* __restrict__ er, int n0, int w, int q, int cc, int N) {
#pragma unroll
  for (int r = 0; r < 4; ++r) {
    int n = n0 + w * 16 + q * 4 + r;
    float pls[4], prs[4];
#pragma unroll
    for (int h = 0; h < 4; ++h) {
      float pl = acc[2 * h][r] * attn_l[h * 32 + cc] +
                 acc[2 * h + 1][r] * attn_l[h * 32 + 16 + cc];
      float pr = acc[2 * h][r] * attn_r[h * 32 + cc] +
                 acc[2 * h + 1][r] * attn_r[h * 32 + 16 + cc];
#pragma unroll
      for (int off = 1; off < 16; off <<= 1) {
        pl += __shfl_xor(pl, off);
        pr += __shfl_xor(pr, off);
      }
      pls[h] = pl;
      prs[h] = pr;
    }
    if (cc == 0 && n < N) {
#pragma unroll
      for (int h = 0; h < 4; ++h) {
        el[n * HEADS + h] = pls[h] * LOG2E;
        er[n * HEADS + h] = prs[h] * LOG2E;
      }
    }
  }
}

// LDS-staged coalesced C store. Each wave owns its 16x128 bf16 slice `my`
// (4 KB): write acc values XOR-swizzled (bank-spread), read back per-row
// 16B chunks, store dwordx4 (1 KB/instr, full lines — no partial-line RMW).
// Same-wave LDS RAW/WAR is ordered by lgkmcnt; no __syncthreads needed.
__device__ __forceinline__ void store_tile(short* my, const f32x4v* acc,
                                           bf16* __restrict__ out, int n0w,
                                           int cc, int q, int lane, int N) {
#pragma unroll
  for (int t = 0; t < 8; ++t) {
#pragma unroll
    for (int r = 0; r < 4; ++r) {
      int row = q * 4 + r;
      int col = t * 16 + cc;
      bf16 hv = __float2bfloat16(acc[t][r]);
      my[row * 128 + (col ^ ((row & 7) << 3))] = *(short*)&hv;
    }
  }
  int row = lane >> 2, qt = lane & 3;
  int n = n0w + row;
  if (n < N) {
    int sw = (row & 7) << 3;
    uint4* gp = (uint4*)&out[(size_t)n * HF + qt * 32];
#pragma unroll
    for (int j = 0; j < 4; ++j) {
      int c0 = qt * 32 + j * 8;
      gp[j] = *(const uint4*)&my[row * 128 + (c0 ^ sw)];
    }
  }
}

// ======= fused: layer-1 dual MFMA GEMM (blocks < gblk) + CSR hist ==========
// Independent: mfma needs only feats+WT (prep0); hist needs only dst+deg.
// mfma blocks first so the long poles start immediately.
__global__ __launch_bounds__(256) void mfma1_hist(
    const float* __restrict__ X, const unsigned* __restrict__ WT1,
    const unsigned* __restrict__ WT2, const float* __restrict__ attn_l,
    const float* __restrict__ attn_r, bf16* __restrict__ outA,
    bf16* __restrict__ outB, float* __restrict__ el, float* __restrict__ er,
    int N, int gblk,
    const int* __restrict__ dst, int* __restrict__ deg,
    int* __restrict__ rank, float* __restrict__ hsum,
    unsigned* __restrict__ hmax, int E, int g32) {
  __shared__ __align__(16) short cst[4][2048];  // 4 waves x 16x128 bf16
  if ((int)blockIdx.x >= gblk) {
    int e = ((int)blockIdx.x - gblk) * 256 + threadIdx.x;
    if (e < g32) {
      hsum[e] = 0.f;
      hmax[e] = NEG_INF_ENC;
    }
    if (e < E) rank[e] = atomicAdd(&deg[dst[e]], 1);
    return;
  }
  const int tid = threadIdx.x;
  const int w = tid >> 6;
  const int lane = tid & 63;
  const int cc = lane & 15;
  const int q = lane >> 4;
  const int n0 = blockIdx.x * 64;
  const int arow = n0 + w * 16 + cc;

  f32x4v acc1[8], acc2[8];
#pragma unroll
  for (int t = 0; t < 8; ++t) {
    acc1[t] = f32x4v{0.f, 0.f, 0.f, 0.f};
    acc2[t] = f32x4v{0.f, 0.f, 0.f, 0.f};
  }

  constexpr int KSTEPS = (IN_FEATS + 31) / 32;
#pragma unroll
  for (int ks = 0; ks < KSTEPS; ++ks) {
    bf16x8v a = load_a_f32<IN_FEATS>(X, arow, N, ks, q);
#pragma unroll
    for (int t = 0; t < 8; ++t) {
      bf16x8v b1 = *(const bf16x8v*)&WT1[(t * 16 + cc) * KP1 + ks * 16 + q * 4];
      bf16x8v b2 = *(const bf16x8v*)&WT2[(t * 16 + cc) * KP1 + ks * 16 + q * 4];
      acc1[t] = __builtin_amdgcn_mfma_f32_16x16x32_bf16(a, b1, acc1[t], 0, 0, 0);
      acc2[t] = __builtin_amdgcn_mfma_f32_16x16x32_bf16(a, b2, acc2[t], 0, 0, 0);
    }
  }
  store_tile(&cst[w][0], acc1, outA, n0 + w * 16, cc, q, lane, N);
  store_tile(&cst[w][0], acc2, outB, n0 + w * 16, cc, q, lane, N);
  scores_epilogue(acc1, attn_l, attn_r, el, er, n0, w, q, cc, N);
}

// Layer 2: X is bf16 (workspace; rows >= N read adjacent workspace, safe).
template <int K, int KP>
__global__ __launch_bounds__(256) void mfma_gemm(
    const bf16* __restrict__ X, const unsigned* __restrict__ WT,
    const float* __restrict__ attn_l, const float* __restrict__ attn_r,
    bf16* __restrict__ out, float* __restrict__ el, float* __restrict__ er,
    int N) {
  __shared__ __align__(16) short cst[4][2048];
  const int tid = threadIdx.x;
  const int w = tid >> 6;
  const int lane = tid & 63;
  const int cc = lane & 15;
  const int q = lane >> 4;
  const int n0 = blockIdx.x * 64;
  const int arow = n0 + w * 16 + cc;

  f32x4v acc[8];
#pragma unroll
  for (int t = 0; t < 8; ++t) acc[t] = f32x4v{0.f, 0.f, 0.f, 0.f};

  constexpr int KSTEPS = (K + 31) / 32;
#pragma unroll
  for (int ks = 0; ks < KSTEPS; ++ks) {
    bf16x8v a = *(const bf16x8v*)&X[(size_t)arow * K + ks * 32 + q * 8];
#pragma unroll
    for (int t = 0; t < 8; ++t) {
      bf16x8v b = *(const bf16x8v*)&WT[(t * 16 + cc) * KP + ks * 16 + q * 4];
      acc[t] = __builtin_amdgcn_mfma_f32_16x16x32_bf16(a, b, acc[t], 0, 0, 0);
    }
  }
  store_tile(&cst[w][0], acc, out, n0 + w * 16, cc, q, lane, N);
  scores_epilogue(acc, attn_l, attn_r, el, er, n0, w, q, cc, N);
}

// ============ fused softmax + aggregate (single edge pass) =================
// One wave per node; lane holds cols (2*lane, 2*lane+1), head h = lane>>4.
// rb/re/s wave-uniform via readfirstlane -> SGPR (s_load + SGPR-base
// gathers). ssorted zero-padded by 16 so no clamps. bpre folded into rb/re.

#define E8_LOAD(i, e_)                                                      \
  const int s##i = __builtin_amdgcn_readfirstlane(ssorted[e_]);             \
  const float xl##i = el[(unsigned)s##i * HEADS + h];                       \
  const unsigned fu##i = *(const unsigned*)&feat[(unsigned)s##i * HF + c2];
#define E8_CALC(i)                                                          \
  {                                                                         \
    float xx = __builtin_amdgcn_exp2f(lrelu(xl##i + ern));                  \
    f32x2v ff;                                                              \
    ff.x = __uint_as_float(fu##i << 16);                                    \
    ff.y = __uint_as_float(fu##i & 0xffff0000u);                            \
    ssum += xx;                                                             \
    axy = __builtin_elementwise_fma(f32x2v{xx, xx}, ff, axy);               \
  }
#define E8_CALC_PRED(i, e_)                                                 \
  {                                                                         \
    float xx = __builtin_amdgcn_exp2f(lrelu(xl##i + ern));                  \
    xx = ((e_) + i < re) ? xx : 0.f;                                        \
    f32x2v ff;                                                              \
    ff.x = __uint_as_float(fu##i << 16);                                    \
    ff.y = __uint_as_float(fu##i & 0xffff0000u);                            \
    ssum += xx;                                                             \
    axy = __builtin_elementwise_fma(f32x2v{xx, xx}, ff, axy);               \
  }

#define AGG_LOOP                                                            \
  f32x2v axy = {0.f, 0.f};                                                  \
  float ssum = 0.f;                                                         \
  const int dg = re - rb;                                                   \
  if (dg <= 8) {                                                            \
    E8_LOAD(0, rb) E8_LOAD(1, rb + 1) E8_LOAD(2, rb + 2)                    \
    E8_LOAD(3, rb + 3) E8_LOAD(4, rb + 4) E8_LOAD(5, rb + 5)                \
    E8_LOAD(6, rb + 6) E8_LOAD(7, rb + 7)                                   \
    E8_CALC_PRED(0, rb) E8_CALC_PRED(1, rb) E8_CALC_PRED(2, rb)             \
    E8_CALC_PRED(3, rb) E8_CALC_PRED(4, rb) E8_CALC_PRED(5, rb)             \
    E8_CALC_PRED(6, rb) E8_CALC_PRED(7, rb)                                 \
  } else if (dg <= 16) {                                                    \
    E8_LOAD(0, rb) E8_LOAD(1, rb + 1) E8_LOAD(2, rb + 2)                    \
    E8_LOAD(3, rb + 3) E8_LOAD(4, rb + 4) E8_LOAD(5, rb + 5)                \
    E8_LOAD(6, rb + 6) E8_LOAD(7, rb + 7)                                   \
    E8_LOAD(8, rb + 8) E8_LOAD(9, rb + 9) E8_LOAD(10, rb + 10)              \
    E8_LOAD(11, rb + 11) E8_LOAD(12, rb + 12) E8_LOAD(13, rb + 13)          \
    E8_LOAD(14, rb + 14) E8_LOAD(15, rb + 15)                               \
    E8_CALC(0) E8_CALC(1) E8_CALC(2) E8_CALC(3)                             \
    E8_CALC(4) E8_CALC(5) E8_CALC(6) E8_CALC(7)                             \
    E8_CALC_PRED(8, rb) E8_CALC_PRED(9, rb) E8_CALC_PRED(10, rb)            \
    E8_CALC_PRED(11, rb) E8_CALC_PRED(12, rb) E8_CALC_PRED(13, rb)          \
    E8_CALC_PRED(14, rb) E8_CALC_PRED(15, rb)                               \
  } else {                                                                  \
    int e = rb;                                                             \
    for (; e + 8 <= re; e += 8) {                                           \
      E8_LOAD(0, e) E8_LOAD(1, e + 1) E8_LOAD(2, e + 2) E8_LOAD(3, e + 3)   \
      E8_LOAD(4, e + 4) E8_LOAD(5, e + 5) E8_LOAD(6, e + 6)                 \
      E8_LOAD(7, e + 7)                                                     \
      E8_CALC(0) E8_CALC(1) E8_CALC(2) E8_CALC(3)                           \
      E8_CALC(4) E8_CALC(5) E8_CALC(6) E8_CALC(7)                           \
    }                                                                       \
    if (e < re) {                                                           \
      E8_LOAD(0, e) E8_LOAD(1, e + 1) E8_LOAD(2, e + 2) E8_LOAD(3, e + 3)   \
      E8_LOAD(4, e + 4) E8_LOAD(5, e + 5) E8_LOAD(6, e + 6)                 \
      E8_LOAD(7, e + 7)                                                     \
      E8_CALC_PRED(0, e) E8_CALC_PRED(1, e) E8_CALC_PRED(2, e)              \
      E8_CALC_PRED(3, e) E8_CALC_PRED(4, e) E8_CALC_PRED(5, e)              \
      E8_CALC_PRED(6, e) E8_CALC_PRED(7, e)                                 \
    }                                                                       \
  }                                                                         \
  float ax = axy.x, ay = axy.y;

// Layer 1 epilogue: H[n] = elu(inv*agg + res[n] + bias)   (res, H bf16)
__global__ __launch_bounds__(256) void agg1_fused(
    const int* __restrict__ row_ptr, const int* __restrict__ bpre,
    const int* __restrict__ ssorted, const float* __restrict__ el,
    const float* __restrict__ er, const bf16* __restrict__ feat,
    const bf16* __restrict__ res, bf16* __restrict__ H,
    const float* __restrict__ bias, int N) {
  int n = blockIdx.x * 4 + (threadIdx.x >> 6);
  if (n >= N) return;
  const int lane = threadIdx.x & 63;
  const int c2 = lane * 2, h = lane >> 4;
  const int rb =
      __builtin_amdgcn_readfirstlane(row_ptr[n] + bpre[n >> 11]);
  const int re =
      __builtin_amdgcn_readfirstlane(row_ptr[n + 1] + bpre[(n + 1) >> 11]);
  const float ern = er[(unsigned)n * HEADS + h];

  AGG_LOOP

  float inv = 1.f / ssum;
  float2 r = unpack_bf16(*(const unsigned*)&res[(unsigned)n * HF + c2]);
  float2 bi = *(const float2*)&bias[c2];
  float vx = fmaf(ax, inv, r.x + bi.x);
  float vy = fmaf(ay, inv, r.y + bi.y);
  vx = (vx > 0.f) ? vx : expm1f(vx);
  vy = (vy > 0.f) ? vy : expm1f(vy);
  *(unsigned*)&H[(unsigned)n * HF + c2] = pack_bf16(vx, vy);
}

// Layer 2 epilogue: head-mean -> sigmoid gate -> readout atomics.
__global__ __launch_bounds__(256) void agg2_fused(
    const int* __restrict__ row_ptr, const int* __restrict__ bpre,
    const int* __restrict__ ssorted, const float* __restrict__ el,
    const float* __restrict__ er, const bf16* __restrict__ feat,
    const bf16* __restrict__ h1, const float* __restrict__ bias,
    const float* __restrict__ ww, const float* __restrict__ wb,
    const int* __restrict__ gids, float* __restrict__ hsum,
    unsigned* __restrict__ hmax, int N) {
  int n = blockIdx.x * 4 + (threadIdx.x >> 6);
  if (n >= N) return;
  const int lane = threadIdx.x & 63;
  const int c2 = lane * 2, h = lane >> 4;
  const int rb =
      __builtin_amdgcn_readfirstlane(row_ptr[n] + bpre[n >> 11]);
  const int re =
      __builtin_amdgcn_readfirstlane(row_ptr[n + 1] + bpre[(n + 1) >> 11]);
  const float ern = er[(unsigned)n * HEADS + h];

  AGG_LOOP

  float inv = 1.f / ssum;
  float2 r = unpack_bf16(*(const unsigned*)&h1[(unsigned)n * HF + c2]);
  float2 bi = *(const float2*)&bias[c2];
  ax = fmaf(ax, inv, r.x + bi.x);
  ay = fmaf(ay, inv, r.y + bi.y);
#pragma unroll
  for (int off = 16; off < 64; off <<= 1) {
    ax += __shfl_xor(ax, off);
    ay += __shfl_xor(ay, off);
  }
  ax *= 0.25f;
  ay *= 0.25f;
  int c = c2 & 31;
  float d = fmaf(ax, ww[c], ay * ww[c + 1]);
#pragma unroll
  for (int off = 1; off < 16; off <<= 1) d += __shfl_xor(d, off);
  float wv = 1.f / (1.f + __expf(-(d + wb[0])));
  if (lane < 16) {
    int g = gids[n];
    atomicAdd(&hsum[g * OUTF + c], wv * ax);
    atomicAdd(&hsum[g * OUTF + c + 1], wv * ay);
    atomicMax(&hmax[g * OUTF + c], enc_f(ax));
    atomicMax(&hmax[g * OUTF + c + 1], enc_f(ay));
  }
}

// ============================ readout tail =================================
__global__ __launch_bounds__(256) void final_gemm_kernel(
    const float* __restrict__ hsum, const unsigned* __restrict__ hmax,
    const float* __restrict__ tw, const float* __restrict__ tb,
    float* __restrict__ out, int G) {
  __shared__ float tws[64 * PRED_DIM];
  for (int i = threadIdx.x; i < 64 * PRED_DIM; i += 256) tws[i] = tw[i];
  __syncthreads();
  int g = blockIdx.x * 2 + (threadIdx.x >> 7);
  int p = threadIdx.x & 127;
  if (g >= G) return;
  float acc = tb[p];
#pragma unroll
  for (int k = 0; k < OUTF; ++k)
    acc = fmaf(hsum[g * OUTF + k], tws[k * PRED_DIM + p], acc);
#pragma unroll
  for (int k = 0; k < OUTF; ++k)
    acc = fmaf(dec_f(hmax[g * OUTF + k]), tws[(OUTF + k) * PRED_DIM + p], acc);
  out[(size_t)g * PRED_DIM + p] = acc;
}

static inline int cdiv(long long a, int b) { return (int)((a + b - 1) / b); }

extern "C" void kernel_launch(void* const* d_in, const int* in_sizes, int n_in,
                              void* d_out, int out_size, void* d_ws,
                              size_t ws_size, hipStream_t stream) {
  const float* feats   = (const float*)d_in[0];
  const int*   src     = (const int*)d_in[1];
  const int*   dst     = (const int*)d_in[2];
  const int*   gids    = (const int*)d_in[3];
  const float* fc1_w   = (const float*)d_in[4];
  const float* attn_l1 = (const float*)d_in[5];
  const float* attn_r1 = (const float*)d_in[6];
  const float* res1_w  = (const float*)d_in[7];
  const float* bias1   = (const float*)d_in[8];
  const float* fc2_w   = (const float*)d_in[9];
  const float* attn_l2 = (const float*)d_in[10];
  const float* attn_r2 = (const float*)d_in[11];
  const float* bias2   = (const float*)d_in[12];
  const float* ww      = (const float*)d_in[13];
  const float* wb      = (const float*)d_in[14];
  const float* tw      = (const float*)d_in[15];
  const float* tb      = (const float*)d_in[16];
  float* out = (float*)d_out;

  const int N = in_sizes[0] / IN_FEATS;  // 100000
  const int E = in_sizes[1];             // 900000
  const int G = out_size / PRED_DIM;     // 2048
  const int NB = cdiv(N, 2048);

  // ---- workspace layout ----
  bf16* A = (bf16*)d_ws;                      // N*128 bf16 (feat1/feat2)
  bf16* B = A + (size_t)N * HF;               // N*128 bf16 (res1)
  bf16* H = B + (size_t)N * HF;               // N*128 bf16 (h1)
  float* el = (float*)(H + (size_t)N * HF);   // N*4
  float* er = el + (size_t)N * HEADS;         // N*4
  float* hsum = er + (size_t)N * HEADS;       // G*32
  unsigned* hmax = (unsigned*)(hsum + (size_t)G * OUTF);  // G*32
  int* deg     = (int*)(hmax + (size_t)G * OUTF);  // N + 1 (last = ticket)
  int* ticket  = deg + N;                          // 1
  int* row_ptr = deg + N + 1;                      // N+1
  int* ssorted = row_ptr + (N + 1);                // E + 16 (padded)
  int* rank    = ssorted + E + 16;                 // E
  int* bsum    = rank + E;                         // NB
  int* bpre    = bsum + NB;                        // NB
  unsigned* WT1 = (unsigned*)(((uintptr_t)(bpre + NB) + 15) &
                              ~(uintptr_t)15);     // 128*KP1, 16B-aligned
  unsigned* WT2 = WT1 + 128 * KP1;                 // 128*KP1
  unsigned* WT3 = WT2 + 128 * KP1;                 // 128*KP2

  const int gblk = cdiv(N, 64);
  const int nwblk = cdiv(N, 4);
  const int SB = cdiv(E, 256);

  // ===================== prep + CSR build =====================
  prep0<<<cdiv(N + 1, 256), 256, 0, stream>>>(fc1_w, res1_w, fc2_w, WT1, WT2,
                                              WT3, deg, N);
  // Layer-1 GEMM overlapped with CSR histogram (independent work).
  mfma1_hist<<<gblk + SB, 256, 0, stream>>>(
      feats, WT1, WT2, attn_l1, attn_r1, A, B, el, er, N, gblk,
      dst, deg, rank, hsum, hmax, E, G * OUTF);
  scan12_kernel<<<NB, 256, 0, stream>>>(deg, row_ptr, bsum, bpre, ticket, N,
                                        E);
  scatter_kernel<<<SB, 256, 0, stream>>>(src, dst, row_ptr, bpre, rank,
                                         ssorted, E);

  // ===================== Layer 1 aggregate =====================
  agg1_fused<<<nwblk, 256, 0, stream>>>(row_ptr, bpre, ssorted, el, er, A, B,
                                        H, bias1, N);

  // ===================== Layer 2 =====================
  mfma_gemm<HF, KP2><<<gblk, 256, 0, stream>>>(
      H, WT3, attn_l2, attn_r2, A, el, er, N);
  agg2_fused<<<nwblk, 256, 0, stream>>>(row_ptr, bpre, ssorted, el, er, A, H,
                                        bias2, ww, wb, gids, hsum, hmax, N);

  // ===================== Readout =====================
  final_gemm_kernel<<<cdiv(G, 2), 256, 0, stream>>>(hsum, hmax, tw, tb, out, G);
}

// Round 8
// 314.889 us; speedup vs baseline: 1.1091x; 1.1091x over previous
//
#include <hip/hip_runtime.h>
#include <hip/hip_bf16.h>

// ---------------------------------------------------------------------------
// DGL GAT (2-layer, heads=4, out=32) + WeightedSumAndMax readout.
// Round 24: base = r22 (345.9, best). Revert r23's store_tile + hist fusion
//           (WRITE_SIZE proved stores were never amplified; LDS/VGPR cost
//           occupancy). New lever: every GEMM wave reads the FULL WT set
//           (98KB dual / 32KB L2-resident) -> all B-loads miss L1 and eat
//           ~200cy each. Stage WT in LDS ONCE per block (single barrier,
//           stride-padded 52/68 dwords -> only free 2-way conflicts);
//           B-fragments become ds_read_b128. GEMM blocks first in the
//           fused grid. C-stores direct (r22 style). 8 dispatches.
// ---------------------------------------------------------------------------

#define HEADS 4
#define OUTF 32
#define HF 128            // HEADS*OUTF
#define IN_FEATS 74
#define PRED_DIM 128
#define NEG_SLOPE 0.2f
#define NEG_INF_ENC 0x007fffffu   // enc_f(-inf)
#define LOG2E 1.4426950408889634f
#define KP1 48            // kpairs for K=74 (padded to 96)
#define KP2 64            // kpairs for K=128
#define LSTR1 52          // LDS row stride (dwords) for KP1; 208B, 16B-mult
#define LSTR2 68          // LDS row stride (dwords) for KP2; 272B, 16B-mult

typedef __hip_bfloat16 bf16;
typedef __hip_bfloat162 bf16x2;
typedef __attribute__((ext_vector_type(8))) short bf16x8v;  // 8 bf16, 4 VGPRs
typedef __attribute__((ext_vector_type(4))) float f32x4v;   // MFMA C/D
typedef __attribute__((ext_vector_type(2))) float f32x2v;   // packed fp32

__device__ __forceinline__ unsigned enc_f(float f) {
  unsigned u = __float_as_uint(f);
  return (u & 0x80000000u) ? ~u : (u | 0x80000000u);
}
__device__ __forceinline__ float dec_f(unsigned k) {
  return (k & 0x80000000u) ? __uint_as_float(k & 0x7fffffffu)
                           : __uint_as_float(~k);
}
__device__ __forceinline__ unsigned pack_bf16(float a, float b) {
  bf16x2 h = __float22bfloat162_rn(make_float2(a, b));
  return *(unsigned*)&h;
}
__device__ __forceinline__ float2 unpack_bf16(unsigned u) {
  bf16x2 h = *(bf16x2*)&u;
  return __bfloat1622float2(h);
}
__device__ __forceinline__ float lrelu(float v) {
  return fmaxf(v, NEG_SLOPE * v);
}

// ============== CSR hist + weight pre-pack (fused, one dispatch) ===========
// deg[] and the scan ticket are zeroed by the preceding hipMemsetAsync.
__global__ __launch_bounds__(256) void hist_prep(
    const int* __restrict__ dst, int* __restrict__ deg,
    int* __restrict__ rank, float* __restrict__ hsum,
    unsigned* __restrict__ hmax, int E, int g32,
    const float* __restrict__ W1, const float* __restrict__ W2,
    const float* __restrict__ W3, unsigned* __restrict__ WT1,
    unsigned* __restrict__ WT2, unsigned* __restrict__ WT3) {
  int t = blockIdx.x * 256 + threadIdx.x;
  if (t < g32) {
    hsum[t] = 0.f;
    hmax[t] = NEG_INF_ENC;
  }
  if (t < 128 * KP1) {
    int c = t / KP1, kp = t % KP1;
    int k = kp * 2;
    float a1 = (k < IN_FEATS) ? W1[k * HF + c] : 0.f;
    float b1 = (k + 1 < IN_FEATS) ? W1[(k + 1) * HF + c] : 0.f;
    float a2 = (k < IN_FEATS) ? W2[k * HF + c] : 0.f;
    float b2 = (k + 1 < IN_FEATS) ? W2[(k + 1) * HF + c] : 0.f;
    WT1[t] = pack_bf16(a1, b1);
    WT2[t] = pack_bf16(a2, b2);
  } else if (t - 128 * KP1 < 128 * KP2) {
    int u = t - 128 * KP1;
    int c = u / KP2, kp = u % KP2;
    int k = kp * 2;
    WT3[u] = pack_bf16(W3[k * HF + c], W3[(k + 1) * HF + c]);
  }
  if (t < E) rank[t] = atomicAdd(&deg[dst[t]], 1);
}

// ===== scan1 + scan2 fused via last-block ticket; also writes row_ptr[N] ===
__global__ __launch_bounds__(256) void scan12_kernel(
    const int* __restrict__ deg, int* __restrict__ row_ptr,
    int* __restrict__ bsum, int* __restrict__ bpre,
    int* __restrict__ ticket, int N, int E) {
  const int base = blockIdx.x * 2048;
  const int tbase = base + threadIdx.x * 8;
  int vals[8];
  int tsum = 0;
#pragma unroll
  for (int i = 0; i < 8; ++i) {
    int idx = tbase + i;
    vals[i] = (idx < N) ? deg[idx] : 0;
    tsum += vals[i];
  }
  const int lane = threadIdx.x & 63, wv = threadIdx.x >> 6;
  int incl = tsum;
#pragma unroll
  for (int off = 1; off < 64; off <<= 1) {
    int nv = __shfl_up(incl, off);
    if (lane >= off) incl += nv;
  }
  __shared__ int wsum[4];
  __shared__ int isLast;
  if (lane == 63) wsum[wv] = incl;
  __syncthreads();
  int woff = 0;
  for (int w = 0; w < wv; ++w) woff += wsum[w];
  int run = woff + incl - tsum;
#pragma unroll
  for (int i = 0; i < 8; ++i) {
    int idx = tbase + i;
    if (idx < N) row_ptr[idx] = run;
    run += vals[i];
  }
  if (threadIdx.x == 255) {
    bsum[blockIdx.x] = woff + incl;
    __threadfence();                       // publish bsum before ticket
    int t = atomicAdd(ticket, 1);
    isLast = (t == (int)gridDim.x - 1);
  }
  __syncthreads();
  if (isLast) {
    if (threadIdx.x < 64) {
      __threadfence();                     // acquire all bsum stores
      const int NB = gridDim.x;
      int running = 0;
      for (int c = 0; c < NB; c += 64) {
        int v = (c + lane < NB) ? bsum[c + lane] : 0;
        int incl2 = v;
#pragma unroll
        for (int off = 1; off < 64; off <<= 1) {
          int nv = __shfl_up(incl2, off);
          if (lane >= off) incl2 += nv;
        }
        if (c + lane < NB) bpre[c + lane] = running + incl2 - v;
        running += __shfl(incl2, 63);
      }
    }
    __syncthreads();                       // drain bpre stores (same CU)
    if (threadIdx.x == 0) row_ptr[N] = E - bpre[N >> 11];
  }
}

// ===================== MFMA node GEMM building blocks ======================
// Fragment mapping (16x16x32 bf16): lane (cc,q) of wave w:
//   A: row n0 + w*16 + cc, kpairs q*4 .. q*4+3
//   B: row t*16 + cc of W (LDS, row stride LSTR dwords), same kpair window
//   C/D: col t*16 + cc, rows n0 + w*16 + q*4 + r

template <int K>
__device__ __forceinline__ bf16x8v load_a_f32(const float* __restrict__ X,
                                              int row, int N, int ks, int q) {
  unsigned v[4] = {0u, 0u, 0u, 0u};
  if (row < N) {
    const float* base = X + (size_t)row * K;
    int k = ks * 32 + q * 8;
#pragma unroll
    for (int j = 0; j < 4; ++j) {
      int kk = k + j * 2;
      if (kk + 1 < K) {
        float2 f = *(const float2*)&base[kk];
        v[j] = pack_bf16(f.x, f.y);
      } else if (kk < K) {
        v[j] = pack_bf16(base[kk], 0.f);
      }
    }
  }
  union { unsigned u[4]; bf16x8v v8; } r;
  r.u[0] = v[0]; r.u[1] = v[1]; r.u[2] = v[2]; r.u[3] = v[3];
  return r.v8;
}

// Cooperative global->LDS copy of one pre-packed W matrix (128 x KP dwords)
// into rows of stride LSTR dwords (16B-multiple so ds ops stay b128).
template <int KP, int LSTR>
__device__ __forceinline__ void stage_w(const unsigned* __restrict__ WT,
                                        unsigned* wl, int tid) {
#pragma unroll
  for (int u = tid; u < 128 * (KP / 4); u += 256) {
    int row = u / (KP / 4), c4 = u % (KP / 4);
    uint4 v = *(const uint4*)&WT[row * KP + c4 * 4];
    *(uint4*)&wl[row * LSTR + c4 * 4] = v;
  }
}

__device__ __forceinline__ void scores_epilogue(
    const f32x4v* acc, const float* __restrict__ attn_l,
    const float* __restrict__ attn_r, float* __restrict__ el,
    float* __restrict__ er, int n0, int w, int q, int cc, int N) {
#pragma unroll
  for (int r = 0; r < 4; ++r) {
    int n = n0 + w * 16 + q * 4 + r;
    float pls[4], prs[4];
#pragma unroll
    for (int h = 0; h < 4; ++h) {
      float pl = acc[2 * h][r] * attn_l[h * 32 + cc] +
                 acc[2 * h + 1][r] * attn_l[h * 32 + 16 + cc];
      float pr = acc[2 * h][r] * attn_r[h * 32 + cc] +
                 acc[2 * h + 1][r] * attn_r[h * 32 + 16 + cc];
#pragma unroll
      for (int off = 1; off < 16; off <<= 1) {
        pl += __shfl_xor(pl, off);
        pr += __shfl_xor(pr, off);
      }
      pls[h] = pl;
      prs[h] = pr;
    }
    if (cc == 0 && n < N) {
#pragma unroll
      for (int h = 0; h < 4; ++h) {
        el[n * HEADS + h] = pls[h] * LOG2E;
        er[n * HEADS + h] = prs[h] * LOG2E;
      }
    }
  }
}

// ===== fused: layer-1 dual MFMA GEMM (blocks < gblk) + CSR scatter =========
// GEMM blocks first (long pole starts immediately). W1/W2 staged in LDS
// once per block; B-fragments are ds_read_b128 (L1-thrash eliminated).
__global__ __launch_bounds__(256) void scat_mfma1(
    const int* __restrict__ src, const int* __restrict__ dst,
    const int* __restrict__ row_ptr, const int* __restrict__ bpre,
    const int* __restrict__ rank, int* __restrict__ ssorted, int E, int gblk,
    const float* __restrict__ X, const unsigned* __restrict__ WT1,
    const unsigned* __restrict__ WT2, const float* __restrict__ attn_l,
    const float* __restrict__ attn_r, bf16* __restrict__ outA,
    bf16* __restrict__ outB, float* __restrict__ el, float* __restrict__ er,
    int N) {
  __shared__ __align__(16) unsigned wlds[2][128 * LSTR1];  // 53.2 KB
  if ((int)blockIdx.x >= gblk) {
    int e = ((int)blockIdx.x - gblk) * 256 + threadIdx.x;
    if (e >= E) return;
    if (e < 16) ssorted[E + e] = 0;
    int d = dst[e];
    ssorted[row_ptr[d] + bpre[d >> 11] + rank[e]] = src[e];
    return;
  }
  const int tid = threadIdx.x;
  stage_w<KP1, LSTR1>(WT1, &wlds[0][0], tid);
  stage_w<KP1, LSTR1>(WT2, &wlds[1][0], tid);
  __syncthreads();

  const int w = tid >> 6;
  const int lane = tid & 63;
  const int cc = lane & 15;
  const int q = lane >> 4;
  const int n0 = blockIdx.x * 64;
  const int arow = n0 + w * 16 + cc;

  f32x4v acc1[8], acc2[8];
#pragma unroll
  for (int t = 0; t < 8; ++t) {
    acc1[t] = f32x4v{0.f, 0.f, 0.f, 0.f};
    acc2[t] = f32x4v{0.f, 0.f, 0.f, 0.f};
  }

  constexpr int KSTEPS = (IN_FEATS + 31) / 32;
#pragma unroll
  for (int ks = 0; ks < KSTEPS; ++ks) {
    bf16x8v a = load_a_f32<IN_FEATS>(X, arow, N, ks, q);
#pragma unroll
    for (int t = 0; t < 8; ++t) {
      bf16x8v b1 =
          *(const bf16x8v*)&wlds[0][(t * 16 + cc) * LSTR1 + ks * 16 + q * 4];
      bf16x8v b2 =
          *(const bf16x8v*)&wlds[1][(t * 16 + cc) * LSTR1 + ks * 16 + q * 4];
      acc1[t] = __builtin_amdgcn_mfma_f32_16x16x32_bf16(a, b1, acc1[t], 0, 0, 0);
      acc2[t] = __builtin_amdgcn_mfma_f32_16x16x32_bf16(a, b2, acc2[t], 0, 0, 0);
    }
  }
#pragma unroll
  for (int r = 0; r < 4; ++r) {
    int n = n0 + w * 16 + q * 4 + r;
    if (n < N) {
#pragma unroll
      for (int t = 0; t < 8; ++t) {
        outA[(size_t)n * HF + t * 16 + cc] = __float2bfloat16(acc1[t][r]);
        outB[(size_t)n * HF + t * 16 + cc] = __float2bfloat16(acc2[t][r]);
      }
    }
  }
  scores_epilogue(acc1, attn_l, attn_r, el, er, n0, w, q, cc, N);
}

// Layer 2: X is bf16 (workspace; rows >= N read adjacent workspace, safe).
// W3 staged in LDS once per block.
template <int K, int KP, int LSTR>
__global__ __launch_bounds__(256) void mfma_gemm(
    const bf16* __restrict__ X, const unsigned* __restrict__ WT,
    const float* __restrict__ attn_l, const float* __restrict__ attn_r,
    bf16* __restrict__ out, float* __restrict__ el, float* __restrict__ er,
    int N) {
  __shared__ __align__(16) unsigned wlds[128 * LSTR];  // 34.8 KB (KP2)
  const int tid = threadIdx.x;
  stage_w<KP, LSTR>(WT, wlds, tid);
  __syncthreads();

  const int w = tid >> 6;
  const int lane = tid & 63;
  const int cc = lane & 15;
  const int q = lane >> 4;
  const int n0 = blockIdx.x * 64;
  const int arow = n0 + w * 16 + cc;

  f32x4v acc[8];
#pragma unroll
  for (int t = 0; t < 8; ++t) acc[t] = f32x4v{0.f, 0.f, 0.f, 0.f};

  constexpr int KSTEPS = (K + 31) / 32;
#pragma unroll
  for (int ks = 0; ks < KSTEPS; ++ks) {
    bf16x8v a = *(const bf16x8v*)&X[(size_t)arow * K + ks * 32 + q * 8];
#pragma unroll
    for (int t = 0; t < 8; ++t) {
      bf16x8v b =
          *(const bf16x8v*)&wlds[(t * 16 + cc) * LSTR + ks * 16 + q * 4];
      acc[t] = __builtin_amdgcn_mfma_f32_16x16x32_bf16(a, b, acc[t], 0, 0, 0);
    }
  }
#pragma unroll
  for (int r = 0; r < 4; ++r) {
    int n = n0 + w * 16 + q * 4 + r;
    if (n < N) {
#pragma unroll
      for (int t = 0; t < 8; ++t)
        out[(size_t)n * HF + t * 16 + cc] = __float2bfloat16(acc[t][r]);
    }
  }
  scores_epilogue(acc, attn_l, attn_r, el, er, n0, w, q, cc, N);
}

// ============ fused softmax + aggregate (single edge pass) =================
// One wave per node; lane holds cols (2*lane, 2*lane+1), head h = lane>>4.
// rb/re/s wave-uniform via readfirstlane -> SGPR (s_load + SGPR-base
// gathers). ssorted zero-padded by 16 so no clamps. bpre folded into rb/re.

#define E8_LOAD(i, e_)                                                      \
  const int s##i = __builtin_amdgcn_readfirstlane(ssorted[e_]);             \
  const float xl##i = el[(unsigned)s##i * HEADS + h];                       \
  const unsigned fu##i = *(const unsigned*)&feat[(unsigned)s##i * HF + c2];
#define E8_CALC(i)                                                          \
  {                                                                         \
    float xx = __builtin_amdgcn_exp2f(lrelu(xl##i + ern));                  \
    f32x2v ff;                                                              \
    ff.x = __uint_as_float(fu##i << 16);                                    \
    ff.y = __uint_as_float(fu##i & 0xffff0000u);                            \
    ssum += xx;                                                             \
    axy = __builtin_elementwise_fma(f32x2v{xx, xx}, ff, axy);               \
  }
#define E8_CALC_PRED(i, e_)                                                 \
  {                                                                         \
    float xx = __builtin_amdgcn_exp2f(lrelu(xl##i + ern));                  \
    xx = ((e_) + i < re) ? xx : 0.f;                                        \
    f32x2v ff;                                                              \
    ff.x = __uint_as_float(fu##i << 16);                                    \
    ff.y = __uint_as_float(fu##i & 0xffff0000u);                            \
    ssum += xx;                                                             \
    axy = __builtin_elementwise_fma(f32x2v{xx, xx}, ff, axy);               \
  }

#define AGG_LOOP                                                            \
  f32x2v axy = {0.f, 0.f};                                                  \
  float ssum = 0.f;                                                         \
  const int dg = re - rb;                                                   \
  if (dg <= 8) {                                                            \
    E8_LOAD(0, rb) E8_LOAD(1, rb + 1) E8_LOAD(2, rb + 2)                    \
    E8_LOAD(3, rb + 3) E8_LOAD(4, rb + 4) E8_LOAD(5, rb + 5)                \
    E8_LOAD(6, rb + 6) E8_LOAD(7, rb + 7)                                   \
    E8_CALC_PRED(0, rb) E8_CALC_PRED(1, rb) E8_CALC_PRED(2, rb)             \
    E8_CALC_PRED(3, rb) E8_CALC_PRED(4, rb) E8_CALC_PRED(5, rb)             \
    E8_CALC_PRED(6, rb) E8_CALC_PRED(7, rb)                                 \
  } else if (dg <= 16) {                                                    \
    E8_LOAD(0, rb) E8_LOAD(1, rb + 1) E8_LOAD(2, rb + 2)                    \
    E8_LOAD(3, rb + 3) E8_LOAD(4, rb + 4) E8_LOAD(5, rb + 5)                \
    E8_LOAD(6, rb + 6) E8_LOAD(7, rb + 7)                                   \
    E8_LOAD(8, rb + 8) E8_LOAD(9, rb + 9) E8_LOAD(10, rb + 10)              \
    E8_LOAD(11, rb + 11) E8_LOAD(12, rb + 12) E8_LOAD(13, rb + 13)          \
    E8_LOAD(14, rb + 14) E8_LOAD(15, rb + 15)                               \
    E8_CALC(0) E8_CALC(1) E8_CALC(2) E8_CALC(3)                             \
    E8_CALC(4) E8_CALC(5) E8_CALC(6) E8_CALC(7)                             \
    E8_CALC_PRED(8, rb) E8_CALC_PRED(9, rb) E8_CALC_PRED(10, rb)            \
    E8_CALC_PRED(11, rb) E8_CALC_PRED(12, rb) E8_CALC_PRED(13, rb)          \
    E8_CALC_PRED(14, rb) E8_CALC_PRED(15, rb)                               \
  } else {                                                                  \
    int e = rb;                                                             \
    for (; e + 8 <= re; e += 8) {                                           \
      E8_LOAD(0, e) E8_LOAD(1, e + 1) E8_LOAD(2, e + 2) E8_LOAD(3, e + 3)   \
      E8_LOAD(4, e + 4) E8_LOAD(5, e + 5) E8_LOAD(6, e + 6)                 \
      E8_LOAD(7, e + 7)                                                     \
      E8_CALC(0) E8_CALC(1) E8_CALC(2) E8_CALC(3)                           \
      E8_CALC(4) E8_CALC(5) E8_CALC(6) E8_CALC(7)                           \
    }                                                                       \
    if (e < re) {                                                           \
      E8_LOAD(0, e) E8_LOAD(1, e + 1) E8_LOAD(2, e + 2) E8_LOAD(3, e + 3)   \
      E8_LOAD(4, e + 4) E8_LOAD(5, e + 5) E8_LOAD(6, e + 6)                 \
      E8_LOAD(7, e + 7)                                                     \
      E8_CALC_PRED(0, e) E8_CALC_PRED(1, e) E8_CALC_PRED(2, e)              \
      E8_CALC_PRED(3, e) E8_CALC_PRED(4, e) E8_CALC_PRED(5, e)              \
      E8_CALC_PRED(6, e) E8_CALC_PRED(7, e)                                 \
    }                                                                       \
  }                                                                         \
  float ax = axy.x, ay = axy.y;

// Layer 1 epilogue: H[n] = elu(inv*agg + res[n] + bias)   (res, H bf16)
__global__ __launch_bounds__(256) void agg1_fused(
    const int* __restrict__ row_ptr, const int* __restrict__ bpre,
    const int* __restrict__ ssorted, const float* __restrict__ el,
    const float* __restrict__ er, const bf16* __restrict__ feat,
    const bf16* __restrict__ res, bf16* __restrict__ H,
    const float* __restrict__ bias, int N) {
  int n = blockIdx.x * 4 + (threadIdx.x >> 6);
  if (n >= N) return;
  const int lane = threadIdx.x & 63;
  const int c2 = lane * 2, h = lane >> 4;
  const int rb =
      __builtin_amdgcn_readfirstlane(row_ptr[n] + bpre[n >> 11]);
  const int re =
      __builtin_amdgcn_readfirstlane(row_ptr[n + 1] + bpre[(n + 1) >> 11]);
  const float ern = er[(unsigned)n * HEADS + h];

  AGG_LOOP

  float inv = 1.f / ssum;
  float2 r = unpack_bf16(*(const unsigned*)&res[(unsigned)n * HF + c2]);
  float2 bi = *(const float2*)&bias[c2];
  float vx = fmaf(ax, inv, r.x + bi.x);
  float vy = fmaf(ay, inv, r.y + bi.y);
  vx = (vx > 0.f) ? vx : expm1f(vx);
  vy = (vy > 0.f) ? vy : expm1f(vy);
  *(unsigned*)&H[(unsigned)n * HF + c2] = pack_bf16(vx, vy);
}

// Layer 2 epilogue: head-mean -> sigmoid gate -> readout atomics.
__global__ __launch_bounds__(256) void agg2_fused(
    const int* __restrict__ row_ptr, const int* __restrict__ bpre,
    const int* __restrict__ ssorted, const float* __restrict__ el,
    const float* __restrict__ er, const bf16* __restrict__ feat,
    const bf16* __restrict__ h1, const float* __restrict__ bias,
    const float* __restrict__ ww, const float* __restrict__ wb,
    const int* __restrict__ gids, float* __restrict__ hsum,
    unsigned* __restrict__ hmax, int N) {
  int n = blockIdx.x * 4 + (threadIdx.x >> 6);
  if (n >= N) return;
  const int lane = threadIdx.x & 63;
  const int c2 = lane * 2, h = lane >> 4;
  const int rb =
      __builtin_amdgcn_readfirstlane(row_ptr[n] + bpre[n >> 11]);
  const int re =
      __builtin_amdgcn_readfirstlane(row_ptr[n + 1] + bpre[(n + 1) >> 11]);
  const float ern = er[(unsigned)n * HEADS + h];

  AGG_LOOP

  float inv = 1.f / ssum;
  float2 r = unpack_bf16(*(const unsigned*)&h1[(unsigned)n * HF + c2]);
  float2 bi = *(const float2*)&bias[c2];
  ax = fmaf(ax, inv, r.x + bi.x);
  ay = fmaf(ay, inv, r.y + bi.y);
#pragma unroll
  for (int off = 16; off < 64; off <<= 1) {
    ax += __shfl_xor(ax, off);
    ay += __shfl_xor(ay, off);
  }
  ax *= 0.25f;
  ay *= 0.25f;
  int c = c2 & 31;
  float d = fmaf(ax, ww[c], ay * ww[c + 1]);
#pragma unroll
  for (int off = 1; off < 16; off <<= 1) d += __shfl_xor(d, off);
  float wv = 1.f / (1.f + __expf(-(d + wb[0])));
  if (lane < 16) {
    int g = gids[n];
    atomicAdd(&hsum[g * OUTF + c], wv * ax);
    atomicAdd(&hsum[g * OUTF + c + 1], wv * ay);
    atomicMax(&hmax[g * OUTF + c], enc_f(ax));
    atomicMax(&hmax[g * OUTF + c + 1], enc_f(ay));
  }
}

// ============================ readout tail =================================
__global__ __launch_bounds__(256) void final_gemm_kernel(
    const float* __restrict__ hsum, const unsigned* __restrict__ hmax,
    const float* __restrict__ tw, const float* __restrict__ tb,
    float* __restrict__ out, int G) {
  __shared__ float tws[64 * PRED_DIM];
  for (int i = threadIdx.x; i < 64 * PRED_DIM; i += 256) tws[i] = tw[i];
  __syncthreads();
  int g = blockIdx.x * 2 + (threadIdx.x >> 7);
  int p = threadIdx.x & 127;
  if (g >= G) return;
  float acc = tb[p];
#pragma unroll
  for (int k = 0; k < OUTF; ++k)
    acc = fmaf(hsum[g * OUTF + k], tws[k * PRED_DIM + p], acc);
#pragma unroll
  for (int k = 0; k < OUTF; ++k)
    acc = fmaf(dec_f(hmax[g * OUTF + k]), tws[(OUTF + k) * PRED_DIM + p], acc);
  out[(size_t)g * PRED_DIM + p] = acc;
}

static inline int cdiv(long long a, int b) { return (int)((a + b - 1) / b); }

extern "C" void kernel_launch(void* const* d_in, const int* in_sizes, int n_in,
                              void* d_out, int out_size, void* d_ws,
                              size_t ws_size, hipStream_t stream) {
  const float* feats   = (const float*)d_in[0];
  const int*   src     = (const int*)d_in[1];
  const int*   dst     = (const int*)d_in[2];
  const int*   gids    = (const int*)d_in[3];
  const float* fc1_w   = (const float*)d_in[4];
  const float* attn_l1 = (const float*)d_in[5];
  const float* attn_r1 = (const float*)d_in[6];
  const float* res1_w  = (const float*)d_in[7];
  const float* bias1   = (const float*)d_in[8];
  const float* fc2_w   = (const float*)d_in[9];
  const float* attn_l2 = (const float*)d_in[10];
  const float* attn_r2 = (const float*)d_in[11];
  const float* bias2   = (const float*)d_in[12];
  const float* ww      = (const float*)d_in[13];
  const float* wb      = (const float*)d_in[14];
  const float* tw      = (const float*)d_in[15];
  const float* tb      = (const float*)d_in[16];
  float* out = (float*)d_out;

  const int N = in_sizes[0] / IN_FEATS;  // 100000
  const int E = in_sizes[1];             // 900000
  const int G = out_size / PRED_DIM;     // 2048
  const int NB = cdiv(N, 2048);

  // ---- workspace layout ----
  bf16* A = (bf16*)d_ws;                      // N*128 bf16 (feat1/feat2)
  bf16* B = A + (size_t)N * HF;               // N*128 bf16 (res1)
  bf16* H = B + (size_t)N * HF;               // N*128 bf16 (h1)
  float* el = (float*)(H + (size_t)N * HF);   // N*4
  float* er = el + (size_t)N * HEADS;         // N*4
  float* hsum = er + (size_t)N * HEADS;       // G*32
  unsigned* hmax = (unsigned*)(hsum + (size_t)G * OUTF);  // G*32
  int* deg     = (int*)(hmax + (size_t)G * OUTF);  // N + 1 (last = ticket)
  int* ticket  = deg + N;                          // 1
  int* row_ptr = deg + N + 1;                      // N+1
  int* ssorted = row_ptr + (N + 1);                // E + 16 (padded)
  int* rank    = ssorted + E + 16;                 // E
  int* bsum    = rank + E;                         // NB
  int* bpre    = bsum + NB;                        // NB
  unsigned* WT1 = (unsigned*)(((uintptr_t)(bpre + NB) + 15) &
                              ~(uintptr_t)15);     // 128*KP1, 16B-aligned
  unsigned* WT2 = WT1 + 128 * KP1;                 // 128*KP1
  unsigned* WT3 = WT2 + 128 * KP1;                 // 128*KP2

  const int gblk = cdiv(N, 64);
  const int nwblk = cdiv(N, 4);
  const int SB = cdiv(E, 256);

  // ===================== prep + CSR build =====================
  hipMemsetAsync(deg, 0, (size_t)(N + 1) * sizeof(int), stream);
  hist_prep<<<SB, 256, 0, stream>>>(dst, deg, rank, hsum, hmax, E, G * OUTF,
                                    fc1_w, res1_w, fc2_w, WT1, WT2, WT3);
  scan12_kernel<<<NB, 256, 0, stream>>>(deg, row_ptr, bsum, bpre, ticket, N,
                                        E);

  // ============ Layer 1 GEMM overlapped with CSR scatter ============
  scat_mfma1<<<gblk + SB, 256, 0, stream>>>(
      src, dst, row_ptr, bpre, rank, ssorted, E, gblk, feats, WT1, WT2,
      attn_l1, attn_r1, A, B, el, er, N);
  agg1_fused<<<nwblk, 256, 0, stream>>>(row_ptr, bpre, ssorted, el, er, A, B,
                                        H, bias1, N);

  // ===================== Layer 2 =====================
  mfma_gemm<HF, KP2, LSTR2><<<gblk, 256, 0, stream>>>(
      H, WT3, attn_l2, attn_r2, A, el, er, N);
  agg2_fused<<<nwblk, 256, 0, stream>>>(row_ptr, bpre, ssorted, el, er, A, H,
                                        bias2, ww, wb, gids, hsum, hmax, N);

  // ===================== Readout =====================
  final_gemm_kernel<<<cdiv(G, 2), 256, 0, stream>>>(hsum, hmax, tw, tb, out, G);
}

// Round 9
// 311.560 us; speedup vs baseline: 1.1209x; 1.0107x over previous
//
#include <hip/hip_runtime.h>
#include <hip/hip_bf16.h>

// ---------------------------------------------------------------------------
// DGL GAT (2-layer, heads=4, out=32) + WeightedSumAndMax readout.
// Round 25: base = r24 (314.9, best). GEMM blocks 256->512 threads
//           (8 waves, 128 nodes/block): same per-block LDS W footprint
//           (53.2/34.8 KB) now feeds 8 waves instead of 4 -> waves/CU
//           12->16 (layer1, VGPR-capped) and 16->32 (layer2). Staging L2
//           re-reads halve (half the blocks). Math/staging/agg/CSR
//           byte-identical to r24. 8 dispatches.
// ---------------------------------------------------------------------------

#define HEADS 4
#define OUTF 32
#define HF 128            // HEADS*OUTF
#define IN_FEATS 74
#define PRED_DIM 128
#define NEG_SLOPE 0.2f
#define NEG_INF_ENC 0x007fffffu   // enc_f(-inf)
#define LOG2E 1.4426950408889634f
#define KP1 48            // kpairs for K=74 (padded to 96)
#define KP2 64            // kpairs for K=128
#define LSTR1 52          // LDS row stride (dwords) for KP1; 208B, 16B-mult
#define LSTR2 68          // LDS row stride (dwords) for KP2; 272B, 16B-mult

typedef __hip_bfloat16 bf16;
typedef __hip_bfloat162 bf16x2;
typedef __attribute__((ext_vector_type(8))) short bf16x8v;  // 8 bf16, 4 VGPRs
typedef __attribute__((ext_vector_type(4))) float f32x4v;   // MFMA C/D
typedef __attribute__((ext_vector_type(2))) float f32x2v;   // packed fp32

__device__ __forceinline__ unsigned enc_f(float f) {
  unsigned u = __float_as_uint(f);
  return (u & 0x80000000u) ? ~u : (u | 0x80000000u);
}
__device__ __forceinline__ float dec_f(unsigned k) {
  return (k & 0x80000000u) ? __uint_as_float(k & 0x7fffffffu)
                           : __uint_as_float(~k);
}
__device__ __forceinline__ unsigned pack_bf16(float a, float b) {
  bf16x2 h = __float22bfloat162_rn(make_float2(a, b));
  return *(unsigned*)&h;
}
__device__ __forceinline__ float2 unpack_bf16(unsigned u) {
  bf16x2 h = *(bf16x2*)&u;
  return __bfloat1622float2(h);
}
__device__ __forceinline__ float lrelu(float v) {
  return fmaxf(v, NEG_SLOPE * v);
}

// ============== CSR hist + weight pre-pack (fused, one dispatch) ===========
// deg[] and the scan ticket are zeroed by the preceding hipMemsetAsync.
__global__ __launch_bounds__(256) void hist_prep(
    const int* __restrict__ dst, int* __restrict__ deg,
    int* __restrict__ rank, float* __restrict__ hsum,
    unsigned* __restrict__ hmax, int E, int g32,
    const float* __restrict__ W1, const float* __restrict__ W2,
    const float* __restrict__ W3, unsigned* __restrict__ WT1,
    unsigned* __restrict__ WT2, unsigned* __restrict__ WT3) {
  int t = blockIdx.x * 256 + threadIdx.x;
  if (t < g32) {
    hsum[t] = 0.f;
    hmax[t] = NEG_INF_ENC;
  }
  if (t < 128 * KP1) {
    int c = t / KP1, kp = t % KP1;
    int k = kp * 2;
    float a1 = (k < IN_FEATS) ? W1[k * HF + c] : 0.f;
    float b1 = (k + 1 < IN_FEATS) ? W1[(k + 1) * HF + c] : 0.f;
    float a2 = (k < IN_FEATS) ? W2[k * HF + c] : 0.f;
    float b2 = (k + 1 < IN_FEATS) ? W2[(k + 1) * HF + c] : 0.f;
    WT1[t] = pack_bf16(a1, b1);
    WT2[t] = pack_bf16(a2, b2);
  } else if (t - 128 * KP1 < 128 * KP2) {
    int u = t - 128 * KP1;
    int c = u / KP2, kp = u % KP2;
    int k = kp * 2;
    WT3[u] = pack_bf16(W3[k * HF + c], W3[(k + 1) * HF + c]);
  }
  if (t < E) rank[t] = atomicAdd(&deg[dst[t]], 1);
}

// ===== scan1 + scan2 fused via last-block ticket; also writes row_ptr[N] ===
__global__ __launch_bounds__(256) void scan12_kernel(
    const int* __restrict__ deg, int* __restrict__ row_ptr,
    int* __restrict__ bsum, int* __restrict__ bpre,
    int* __restrict__ ticket, int N, int E) {
  const int base = blockIdx.x * 2048;
  const int tbase = base + threadIdx.x * 8;
  int vals[8];
  int tsum = 0;
#pragma unroll
  for (int i = 0; i < 8; ++i) {
    int idx = tbase + i;
    vals[i] = (idx < N) ? deg[idx] : 0;
    tsum += vals[i];
  }
  const int lane = threadIdx.x & 63, wv = threadIdx.x >> 6;
  int incl = tsum;
#pragma unroll
  for (int off = 1; off < 64; off <<= 1) {
    int nv = __shfl_up(incl, off);
    if (lane >= off) incl += nv;
  }
  __shared__ int wsum[4];
  __shared__ int isLast;
  if (lane == 63) wsum[wv] = incl;
  __syncthreads();
  int woff = 0;
  for (int w = 0; w < wv; ++w) woff += wsum[w];
  int run = woff + incl - tsum;
#pragma unroll
  for (int i = 0; i < 8; ++i) {
    int idx = tbase + i;
    if (idx < N) row_ptr[idx] = run;
    run += vals[i];
  }
  if (threadIdx.x == 255) {
    bsum[blockIdx.x] = woff + incl;
    __threadfence();                       // publish bsum before ticket
    int t = atomicAdd(ticket, 1);
    isLast = (t == (int)gridDim.x - 1);
  }
  __syncthreads();
  if (isLast) {
    if (threadIdx.x < 64) {
      __threadfence();                     // acquire all bsum stores
      const int NB = gridDim.x;
      int running = 0;
      for (int c = 0; c < NB; c += 64) {
        int v = (c + lane < NB) ? bsum[c + lane] : 0;
        int incl2 = v;
#pragma unroll
        for (int off = 1; off < 64; off <<= 1) {
          int nv = __shfl_up(incl2, off);
          if (lane >= off) incl2 += nv;
        }
        if (c + lane < NB) bpre[c + lane] = running + incl2 - v;
        running += __shfl(incl2, 63);
      }
    }
    __syncthreads();                       // drain bpre stores (same CU)
    if (threadIdx.x == 0) row_ptr[N] = E - bpre[N >> 11];
  }
}

// ===================== MFMA node GEMM building blocks ======================
// Fragment mapping (16x16x32 bf16): lane (cc,q) of wave w:
//   A: row n0 + w*16 + cc, kpairs q*4 .. q*4+3
//   B: row t*16 + cc of W (LDS, row stride LSTR dwords), same kpair window
//   C/D: col t*16 + cc, rows n0 + w*16 + q*4 + r

template <int K>
__device__ __forceinline__ bf16x8v load_a_f32(const float* __restrict__ X,
                                              int row, int N, int ks, int q) {
  unsigned v[4] = {0u, 0u, 0u, 0u};
  if (row < N) {
    const float* base = X + (size_t)row * K;
    int k = ks * 32 + q * 8;
#pragma unroll
    for (int j = 0; j < 4; ++j) {
      int kk = k + j * 2;
      if (kk + 1 < K) {
        float2 f = *(const float2*)&base[kk];
        v[j] = pack_bf16(f.x, f.y);
      } else if (kk < K) {
        v[j] = pack_bf16(base[kk], 0.f);
      }
    }
  }
  union { unsigned u[4]; bf16x8v v8; } r;
  r.u[0] = v[0]; r.u[1] = v[1]; r.u[2] = v[2]; r.u[3] = v[3];
  return r.v8;
}

// Cooperative global->LDS copy of one pre-packed W matrix (128 x KP dwords)
// into rows of stride LSTR dwords (16B-multiple so ds ops stay b128).
template <int KP, int LSTR, int THREADS>
__device__ __forceinline__ void stage_w(const unsigned* __restrict__ WT,
                                        unsigned* wl, int tid) {
#pragma unroll
  for (int u = tid; u < 128 * (KP / 4); u += THREADS) {
    int row = u / (KP / 4), c4 = u % (KP / 4);
    uint4 v = *(const uint4*)&WT[row * KP + c4 * 4];
    *(uint4*)&wl[row * LSTR + c4 * 4] = v;
  }
}

__device__ __forceinline__ void scores_epilogue(
    const f32x4v* acc, const float* __restrict__ attn_l,
    const float* __restrict__ attn_r, float* __restrict__ el,
    float* __restrict__ er, int n0, int w, int q, int cc, int N) {
#pragma unroll
  for (int r = 0; r < 4; ++r) {
    int n = n0 + w * 16 + q * 4 + r;
    float pls[4], prs[4];
#pragma unroll
    for (int h = 0; h < 4; ++h) {
      float pl = acc[2 * h][r] * attn_l[h * 32 + cc] +
                 acc[2 * h + 1][r] * attn_l[h * 32 + 16 + cc];
      float pr = acc[2 * h][r] * attn_r[h * 32 + cc] +
                 acc[2 * h + 1][r] * attn_r[h * 32 + 16 + cc];
#pragma unroll
      for (int off = 1; off < 16; off <<= 1) {
        pl += __shfl_xor(pl, off);
        pr += __shfl_xor(pr, off);
      }
      pls[h] = pl;
      prs[h] = pr;
    }
    if (cc == 0 && n < N) {
#pragma unroll
      for (int h = 0; h < 4; ++h) {
        el[n * HEADS + h] = pls[h] * LOG2E;
        er[n * HEADS + h] = prs[h] * LOG2E;
      }
    }
  }
}

// ===== fused: layer-1 dual MFMA GEMM (blocks < gblk) + CSR scatter =========
// 512-thread blocks: 8 waves share one LDS W copy (128 nodes/block).
__global__ __launch_bounds__(512) void scat_mfma1(
    const int* __restrict__ src, const int* __restrict__ dst,
    const int* __restrict__ row_ptr, const int* __restrict__ bpre,
    const int* __restrict__ rank, int* __restrict__ ssorted, int E, int gblk,
    const float* __restrict__ X, const unsigned* __restrict__ WT1,
    const unsigned* __restrict__ WT2, const float* __restrict__ attn_l,
    const float* __restrict__ attn_r, bf16* __restrict__ outA,
    bf16* __restrict__ outB, float* __restrict__ el, float* __restrict__ er,
    int N) {
  __shared__ __align__(16) unsigned wlds[2][128 * LSTR1];  // 53.2 KB
  if ((int)blockIdx.x >= gblk) {
    int e = ((int)blockIdx.x - gblk) * 512 + threadIdx.x;
    if (e >= E) return;
    if (e < 16) ssorted[E + e] = 0;
    int d = dst[e];
    ssorted[row_ptr[d] + bpre[d >> 11] + rank[e]] = src[e];
    return;
  }
  const int tid = threadIdx.x;
  stage_w<KP1, LSTR1, 512>(WT1, &wlds[0][0], tid);
  stage_w<KP1, LSTR1, 512>(WT2, &wlds[1][0], tid);
  __syncthreads();

  const int w = tid >> 6;
  const int lane = tid & 63;
  const int cc = lane & 15;
  const int q = lane >> 4;
  const int n0 = blockIdx.x * 128;
  const int arow = n0 + w * 16 + cc;

  f32x4v acc1[8], acc2[8];
#pragma unroll
  for (int t = 0; t < 8; ++t) {
    acc1[t] = f32x4v{0.f, 0.f, 0.f, 0.f};
    acc2[t] = f32x4v{0.f, 0.f, 0.f, 0.f};
  }

  constexpr int KSTEPS = (IN_FEATS + 31) / 32;
#pragma unroll
  for (int ks = 0; ks < KSTEPS; ++ks) {
    bf16x8v a = load_a_f32<IN_FEATS>(X, arow, N, ks, q);
#pragma unroll
    for (int t = 0; t < 8; ++t) {
      bf16x8v b1 =
          *(const bf16x8v*)&wlds[0][(t * 16 + cc) * LSTR1 + ks * 16 + q * 4];
      bf16x8v b2 =
          *(const bf16x8v*)&wlds[1][(t * 16 + cc) * LSTR1 + ks * 16 + q * 4];
      acc1[t] = __builtin_amdgcn_mfma_f32_16x16x32_bf16(a, b1, acc1[t], 0, 0, 0);
      acc2[t] = __builtin_amdgcn_mfma_f32_16x16x32_bf16(a, b2, acc2[t], 0, 0, 0);
    }
  }
#pragma unroll
  for (int r = 0; r < 4; ++r) {
    int n = n0 + w * 16 + q * 4 + r;
    if (n < N) {
#pragma unroll
      for (int t = 0; t < 8; ++t) {
        outA[(size_t)n * HF + t * 16 + cc] = __float2bfloat16(acc1[t][r]);
        outB[(size_t)n * HF + t * 16 + cc] = __float2bfloat16(acc2[t][r]);
      }
    }
  }
  scores_epilogue(acc1, attn_l, attn_r, el, er, n0, w, q, cc, N);
}

// Layer 2: X is bf16 (workspace; rows >= N read adjacent workspace, safe).
// W3 staged in LDS once per 512-thread block (34.8 KB -> up to 32 waves/CU).
template <int K, int KP, int LSTR>
__global__ __launch_bounds__(512) void mfma_gemm(
    const bf16* __restrict__ X, const unsigned* __restrict__ WT,
    const float* __restrict__ attn_l, const float* __restrict__ attn_r,
    bf16* __restrict__ out, float* __restrict__ el, float* __restrict__ er,
    int N) {
  __shared__ __align__(16) unsigned wlds[128 * LSTR];  // 34.8 KB (KP2)
  const int tid = threadIdx.x;
  stage_w<KP, LSTR, 512>(WT, wlds, tid);
  __syncthreads();

  const int w = tid >> 6;
  const int lane = tid & 63;
  const int cc = lane & 15;
  const int q = lane >> 4;
  const int n0 = blockIdx.x * 128;
  const int arow = n0 + w * 16 + cc;

  f32x4v acc[8];
#pragma unroll
  for (int t = 0; t < 8; ++t) acc[t] = f32x4v{0.f, 0.f, 0.f, 0.f};

  constexpr int KSTEPS = (K + 31) / 32;
#pragma unroll
  for (int ks = 0; ks < KSTEPS; ++ks) {
    bf16x8v a = *(const bf16x8v*)&X[(size_t)arow * K + ks * 32 + q * 8];
#pragma unroll
    for (int t = 0; t < 8; ++t) {
      bf16x8v b =
          *(const bf16x8v*)&wlds[(t * 16 + cc) * LSTR + ks * 16 + q * 4];
      acc[t] = __builtin_amdgcn_mfma_f32_16x16x32_bf16(a, b, acc[t], 0, 0, 0);
    }
  }
#pragma unroll
  for (int r = 0; r < 4; ++r) {
    int n = n0 + w * 16 + q * 4 + r;
    if (n < N) {
#pragma unroll
      for (int t = 0; t < 8; ++t)
        out[(size_t)n * HF + t * 16 + cc] = __float2bfloat16(acc[t][r]);
    }
  }
  scores_epilogue(acc, attn_l, attn_r, el, er, n0, w, q, cc, N);
}

// ============ fused softmax + aggregate (single edge pass) =================
// One wave per node; lane holds cols (2*lane, 2*lane+1), head h = lane>>4.
// rb/re/s wave-uniform via readfirstlane -> SGPR (s_load + SGPR-base
// gathers). ssorted zero-padded by 16 so no clamps. bpre folded into rb/re.

#define E8_LOAD(i, e_)                                                      \
  const int s##i = __builtin_amdgcn_readfirstlane(ssorted[e_]);             \
  const float xl##i = el[(unsigned)s##i * HEADS + h];                       \
  const unsigned fu##i = *(const unsigned*)&feat[(unsigned)s##i * HF + c2];
#define E8_CALC(i)                                                          \
  {                                                                         \
    float xx = __builtin_amdgcn_exp2f(lrelu(xl##i + ern));                  \
    f32x2v ff;                                                              \
    ff.x = __uint_as_float(fu##i << 16);                                    \
    ff.y = __uint_as_float(fu##i & 0xffff0000u);                            \
    ssum += xx;                                                             \
    axy = __builtin_elementwise_fma(f32x2v{xx, xx}, ff, axy);               \
  }
#define E8_CALC_PRED(i, e_)                                                 \
  {                                                                         \
    float xx = __builtin_amdgcn_exp2f(lrelu(xl##i + ern));                  \
    xx = ((e_) + i < re) ? xx : 0.f;                                        \
    f32x2v ff;                                                              \
    ff.x = __uint_as_float(fu##i << 16);                                    \
    ff.y = __uint_as_float(fu##i & 0xffff0000u);                            \
    ssum += xx;                                                             \
    axy = __builtin_elementwise_fma(f32x2v{xx, xx}, ff, axy);               \
  }

#define AGG_LOOP                                                            \
  f32x2v axy = {0.f, 0.f};                                                  \
  float ssum = 0.f;                                                         \
  const int dg = re - rb;                                                   \
  if (dg <= 8) {                                                            \
    E8_LOAD(0, rb) E8_LOAD(1, rb + 1) E8_LOAD(2, rb + 2)                    \
    E8_LOAD(3, rb + 3) E8_LOAD(4, rb + 4) E8_LOAD(5, rb + 5)                \
    E8_LOAD(6, rb + 6) E8_LOAD(7, rb + 7)                                   \
    E8_CALC_PRED(0, rb) E8_CALC_PRED(1, rb) E8_CALC_PRED(2, rb)             \
    E8_CALC_PRED(3, rb) E8_CALC_PRED(4, rb) E8_CALC_PRED(5, rb)             \
    E8_CALC_PRED(6, rb) E8_CALC_PRED(7, rb)                                 \
  } else if (dg <= 16) {                                                    \
    E8_LOAD(0, rb) E8_LOAD(1, rb + 1) E8_LOAD(2, rb + 2)                    \
    E8_LOAD(3, rb + 3) E8_LOAD(4, rb + 4) E8_LOAD(5, rb + 5)                \
    E8_LOAD(6, rb + 6) E8_LOAD(7, rb + 7)                                   \
    E8_LOAD(8, rb + 8) E8_LOAD(9, rb + 9) E8_LOAD(10, rb + 10)              \
    E8_LOAD(11, rb + 11) E8_LOAD(12, rb + 12) E8_LOAD(13, rb + 13)          \
    E8_LOAD(14, rb + 14) E8_LOAD(15, rb + 15)                               \
    E8_CALC(0) E8_CALC(1) E8_CALC(2) E8_CALC(3)                             \
    E8_CALC(4) E8_CALC(5) E8_CALC(6) E8_CALC(7)                             \
    E8_CALC_PRED(8, rb) E8_CALC_PRED(9, rb) E8_CALC_PRED(10, rb)            \
    E8_CALC_PRED(11, rb) E8_CALC_PRED(12, rb) E8_CALC_PRED(13, rb)          \
    E8_CALC_PRED(14, rb) E8_CALC_PRED(15, rb)                               \
  } else {                                                                  \
    int e = rb;                                                             \
    for (; e + 8 <= re; e += 8) {                                           \
      E8_LOAD(0, e) E8_LOAD(1, e + 1) E8_LOAD(2, e + 2) E8_LOAD(3, e + 3)   \
      E8_LOAD(4, e + 4) E8_LOAD(5, e + 5) E8_LOAD(6, e + 6)                 \
      E8_LOAD(7, e + 7)                                                     \
      E8_CALC(0) E8_CALC(1) E8_CALC(2) E8_CALC(3)                           \
      E8_CALC(4) E8_CALC(5) E8_CALC(6) E8_CALC(7)                           \
    }                                                                       \
    if (e < re) {                                                           \
      E8_LOAD(0, e) E8_LOAD(1, e + 1) E8_LOAD(2, e + 2) E8_LOAD(3, e + 3)   \
      E8_LOAD(4, e + 4) E8_LOAD(5, e + 5) E8_LOAD(6, e + 6)                 \
      E8_LOAD(7, e + 7)                                                     \
      E8_CALC_PRED(0, e) E8_CALC_PRED(1, e) E8_CALC_PRED(2, e)              \
      E8_CALC_PRED(3, e) E8_CALC_PRED(4, e) E8_CALC_PRED(5, e)              \
      E8_CALC_PRED(6, e) E8_CALC_PRED(7, e)                                 \
    }                                                                       \
  }                                                                         \
  float ax = axy.x, ay = axy.y;

// Layer 1 epilogue: H[n] = elu(inv*agg + res[n] + bias)   (res, H bf16)
__global__ __launch_bounds__(256) void agg1_fused(
    const int* __restrict__ row_ptr, const int* __restrict__ bpre,
    const int* __restrict__ ssorted, const float* __restrict__ el,
    const float* __restrict__ er, const bf16* __restrict__ feat,
    const bf16* __restrict__ res, bf16* __restrict__ H,
    const float* __restrict__ bias, int N) {
  int n = blockIdx.x * 4 + (threadIdx.x >> 6);
  if (n >= N) return;
  const int lane = threadIdx.x & 63;
  const int c2 = lane * 2, h = lane >> 4;
  const int rb =
      __builtin_amdgcn_readfirstlane(row_ptr[n] + bpre[n >> 11]);
  const int re =
      __builtin_amdgcn_readfirstlane(row_ptr[n + 1] + bpre[(n + 1) >> 11]);
  const float ern = er[(unsigned)n * HEADS + h];

  AGG_LOOP

  float inv = 1.f / ssum;
  float2 r = unpack_bf16(*(const unsigned*)&res[(unsigned)n * HF + c2]);
  float2 bi = *(const float2*)&bias[c2];
  float vx = fmaf(ax, inv, r.x + bi.x);
  float vy = fmaf(ay, inv, r.y + bi.y);
  vx = (vx > 0.f) ? vx : expm1f(vx);
  vy = (vy > 0.f) ? vy : expm1f(vy);
  *(unsigned*)&H[(unsigned)n * HF + c2] = pack_bf16(vx, vy);
}

// Layer 2 epilogue: head-mean -> sigmoid gate -> readout atomics.
__global__ __launch_bounds__(256) void agg2_fused(
    const int* __restrict__ row_ptr, const int* __restrict__ bpre,
    const int* __restrict__ ssorted, const float* __restrict__ el,
    const float* __restrict__ er, const bf16* __restrict__ feat,
    const bf16* __restrict__ h1, const float* __restrict__ bias,
    const float* __restrict__ ww, const float* __restrict__ wb,
    const int* __restrict__ gids, float* __restrict__ hsum,
    unsigned* __restrict__ hmax, int N) {
  int n = blockIdx.x * 4 + (threadIdx.x >> 6);
  if (n >= N) return;
  const int lane = threadIdx.x & 63;
  const int c2 = lane * 2, h = lane >> 4;
  const int rb =
      __builtin_amdgcn_readfirstlane(row_ptr[n] + bpre[n >> 11]);
  const int re =
      __builtin_amdgcn_readfirstlane(row_ptr[n + 1] + bpre[(n + 1) >> 11]);
  const float ern = er[(unsigned)n * HEADS + h];

  AGG_LOOP

  float inv = 1.f / ssum;
  float2 r = unpack_bf16(*(const unsigned*)&h1[(unsigned)n * HF + c2]);
  float2 bi = *(const float2*)&bias[c2];
  ax = fmaf(ax, inv, r.x + bi.x);
  ay = fmaf(ay, inv, r.y + bi.y);
#pragma unroll
  for (int off = 16; off < 64; off <<= 1) {
    ax += __shfl_xor(ax, off);
    ay += __shfl_xor(ay, off);
  }
  ax *= 0.25f;
  ay *= 0.25f;
  int c = c2 & 31;
  float d = fmaf(ax, ww[c], ay * ww[c + 1]);
#pragma unroll
  for (int off = 1; off < 16; off <<= 1) d += __shfl_xor(d, off);
  float wv = 1.f / (1.f + __expf(-(d + wb[0])));
  if (lane < 16) {
    int g = gids[n];
    atomicAdd(&hsum[g * OUTF + c], wv * ax);
    atomicAdd(&hsum[g * OUTF + c + 1], wv * ay);
    atomicMax(&hmax[g * OUTF + c], enc_f(ax));
    atomicMax(&hmax[g * OUTF + c + 1], enc_f(ay));
  }
}

// ============================ readout tail =================================
__global__ __launch_bounds__(256) void final_gemm_kernel(
    const float* __restrict__ hsum, const unsigned* __restrict__ hmax,
    const float* __restrict__ tw, const float* __restrict__ tb,
    float* __restrict__ out, int G) {
  __shared__ float tws[64 * PRED_DIM];
  for (int i = threadIdx.x; i < 64 * PRED_DIM; i += 256) tws[i] = tw[i];
  __syncthreads();
  int g = blockIdx.x * 2 + (threadIdx.x >> 7);
  int p = threadIdx.x & 127;
  if (g >= G) return;
  float acc = tb[p];
#pragma unroll
  for (int k = 0; k < OUTF; ++k)
    acc = fmaf(hsum[g * OUTF + k], tws[k * PRED_DIM + p], acc);
#pragma unroll
  for (int k = 0; k < OUTF; ++k)
    acc = fmaf(dec_f(hmax[g * OUTF + k]), tws[(OUTF + k) * PRED_DIM + p], acc);
  out[(size_t)g * PRED_DIM + p] = acc;
}

static inline int cdiv(long long a, int b) { return (int)((a + b - 1) / b); }

extern "C" void kernel_launch(void* const* d_in, const int* in_sizes, int n_in,
                              void* d_out, int out_size, void* d_ws,
                              size_t ws_size, hipStream_t stream) {
  const float* feats   = (const float*)d_in[0];
  const int*   src     = (const int*)d_in[1];
  const int*   dst     = (const int*)d_in[2];
  const int*   gids    = (const int*)d_in[3];
  const float* fc1_w   = (const float*)d_in[4];
  const float* attn_l1 = (const float*)d_in[5];
  const float* attn_r1 = (const float*)d_in[6];
  const float* res1_w  = (const float*)d_in[7];
  const float* bias1   = (const float*)d_in[8];
  const float* fc2_w   = (const float*)d_in[9];
  const float* attn_l2 = (const float*)d_in[10];
  const float* attn_r2 = (const float*)d_in[11];
  const float* bias2   = (const float*)d_in[12];
  const float* ww      = (const float*)d_in[13];
  const float* wb      = (const float*)d_in[14];
  const float* tw      = (const float*)d_in[15];
  const float* tb      = (const float*)d_in[16];
  float* out = (float*)d_out;

  const int N = in_sizes[0] / IN_FEATS;  // 100000
  const int E = in_sizes[1];             // 900000
  const int G = out_size / PRED_DIM;     // 2048
  const int NB = cdiv(N, 2048);

  // ---- workspace layout ----
  bf16* A = (bf16*)d_ws;                      // N*128 bf16 (feat1/feat2)
  bf16* B = A + (size_t)N * HF;               // N*128 bf16 (res1)
  bf16* H = B + (size_t)N * HF;               // N*128 bf16 (h1)
  float* el = (float*)(H + (size_t)N * HF);   // N*4
  float* er = el + (size_t)N * HEADS;         // N*4
  float* hsum = er + (size_t)N * HEADS;       // G*32
  unsigned* hmax = (unsigned*)(hsum + (size_t)G * OUTF);  // G*32
  int* deg     = (int*)(hmax + (size_t)G * OUTF);  // N + 1 (last = ticket)
  int* ticket  = deg + N;                          // 1
  int* row_ptr = deg + N + 1;                      // N+1
  int* ssorted = row_ptr + (N + 1);                // E + 16 (padded)
  int* rank    = ssorted + E + 16;                 // E
  int* bsum    = rank + E;                         // NB
  int* bpre    = bsum + NB;                        // NB
  unsigned* WT1 = (unsigned*)(((uintptr_t)(bpre + NB) + 15) &
                              ~(uintptr_t)15);     // 128*KP1, 16B-aligned
  unsigned* WT2 = WT1 + 128 * KP1;                 // 128*KP1
  unsigned* WT3 = WT2 + 128 * KP1;                 // 128*KP2

  const int gblk = cdiv(N, 128);       // 512-thread GEMM blocks
  const int nwblk = cdiv(N, 4);
  const int SB = cdiv(E, 256);
  const int SB512 = cdiv(E, 512);

  // ===================== prep + CSR build =====================
  hipMemsetAsync(deg, 0, (size_t)(N + 1) * sizeof(int), stream);
  hist_prep<<<SB, 256, 0, stream>>>(dst, deg, rank, hsum, hmax, E, G * OUTF,
                                    fc1_w, res1_w, fc2_w, WT1, WT2, WT3);
  scan12_kernel<<<NB, 256, 0, stream>>>(deg, row_ptr, bsum, bpre, ticket, N,
                                        E);

  // ============ Layer 1 GEMM overlapped with CSR scatter ============
  scat_mfma1<<<gblk + SB512, 512, 0, stream>>>(
      src, dst, row_ptr, bpre, rank, ssorted, E, gblk, feats, WT1, WT2,
      attn_l1, attn_r1, A, B, el, er, N);
  agg1_fused<<<nwblk, 256, 0, stream>>>(row_ptr, bpre, ssorted, el, er, A, B,
                                        H, bias1, N);

  // ===================== Layer 2 =====================
  mfma_gemm<HF, KP2, LSTR2><<<gblk, 512, 0, stream>>>(
      H, WT3, attn_l2, attn_r2, A, el, er, N);
  agg2_fused<<<nwblk, 256, 0, stream>>>(row_ptr, bpre, ssorted, el, er, A, H,
                                        bias2, ww, wb, gids, hsum, hmax, N);

  // ===================== Readout =====================
  final_gemm_kernel<<<cdiv(G, 2), 256, 0, stream>>>(hsum, hmax, tw, tb, out, G);
}